// Round 16
// baseline (199.599 us; speedup 1.0000x reference)
//
#include <hip/hip_runtime.h>
#include <hip/hip_bf16.h>

// MetaConv2d fused hypernetwork + dynamic conv, bf16 MFMA. Round 16.
// = round-6 structure (measured best, 140-143us) made PERSISTENT:
//   grid 256 (1 block/CU), each block processes 4 node-groups of 8 nodes.
//   Group g+1's x slab is prefetched into REGISTERS (T14) during group g's
//   last phase and ds-written after g's epilogue -> the per-group x-stage
//   serial head (the only unoverlapped cost at 1-block/CU residency) is
//   hidden for 3 of 4 groups; epilogue stores overlap next group's hyper.
// All barriers are lgkm-only (r7's proven helper): every cross-thread dep is
// through LDS, and __syncthreads' vmcnt(0) drain would kill the in-flight
// x prefetch at the phase boundary.
// Everything else identical to r6: 8 nodes/group, 1024 thr (16 waves =
// node x t-half), 4 phases (2 c-chunks x 2 o-halves), hyper 12 tiles/wave
// (2 groups of 6), conv B[2][3] + XOR-swizzled A, static acc[2][4].

#define BN_TOT   8192
#define C_IN     64
#define C_OUT    64
#define M_DIM    32
#define S_OUT    62

#define NT       8            // nodes per group
#define GRPS     4            // groups per persistent block
#define NTHREADS 1024         // 16 waves
#define OSTR     104          // shorts per o-row in w_lds (96 j + 8 pad, odd dwords)
#define NODESTR  3336         // 32*OSTR + 8
#define WLDSN    (NT * NODESTR)      // 26688 shorts
#define XLDSN    (NT * 64 * 64)      // 32768 shorts (x bf16, swizzled)
#define DYNB     ((XLDSN + WLDSN) * 2)   // 118912 B
#define WLW_ROWS 12288
#define WS_NEED  (WLW_ROWS * M_DIM * 2 + WLW_ROWS * 4)

typedef __attribute__((ext_vector_type(8))) short bf16x8;
typedef __attribute__((ext_vector_type(4))) float f32x4;

static __device__ __forceinline__ short f2bf(float f) {
    return __bfloat16_as_short(__float2bfloat16(f));
}

static __device__ __forceinline__ bf16x8 cvt8(float4 a, float4 b) {
    bf16x8 r;
    r[0] = f2bf(a.x); r[1] = f2bf(a.y); r[2] = f2bf(a.z); r[3] = f2bf(a.w);
    r[4] = f2bf(b.x); r[5] = f2bf(b.y); r[6] = f2bf(b.z); r[7] = f2bf(b.w);
    return r;
}

// LDS-visibility-only barrier: does NOT drain vmcnt, so prefetch loads stay
// in flight across phase boundaries. All cross-thread deps here are LDS.
static __device__ __forceinline__ void barrier_lgkm() {
    asm volatile("s_waitcnt lgkmcnt(0)" ::: "memory");
    __builtin_amdgcn_s_barrier();
    asm volatile("" ::: "memory");
}

// ---------------- pre-pass 1: w_lin_w f32 -> bf16 ----------------
extern "C" __global__ void wlw_to_bf16(const float* __restrict__ src,
                                       short* __restrict__ dst) {
    const int i = (blockIdx.x * 256 + threadIdx.x) * 8;
    const float4 a = *reinterpret_cast<const float4*>(src + i);
    const float4 b = *reinterpret_cast<const float4*>(src + i + 4);
    *reinterpret_cast<bf16x8*>(dst + i) = cvt8(a, b);
}

// ---------------- pre-pass 2: wlb -> wlbR[o][k][c] f32 ----------------
extern "C" __global__ void wlb_rearr(const float* __restrict__ wlb,
                                     float* __restrict__ wlbR) {
    const int i = blockIdx.x * 256 + threadIdx.x;
    const int o = i / 192;
    const int r = i - o * 192;
    const int k = r >> 6;
    const int c = r & 63;
    wlbR[i] = wlb[o * 192 + c * 3 + k];
}

// ---------------- fused persistent kernel ----------------
template <int USE_WS>
__global__ void __launch_bounds__(NTHREADS, 4)
metaconv_fused(const float* __restrict__ meta,   // [8192][32]
               const float* __restrict__ x,      // [8192][64][64]
               const float* __restrict__ wlw,    // [12288][32] f32
               const short* __restrict__ wlwbf,  // [12288][32] bf16 (ws)
               const float* __restrict__ wlb,    // [12288]
               const float* __restrict__ wlbR,   // [64][3][64] (ws)
               const float* __restrict__ blw,    // [64][32]
               const float* __restrict__ blb,    // [64]
               float* __restrict__ out)          // [8192][62][64]
{
    extern __shared__ __align__(16) short dynsm[];
    short* xsh = dynsm;                  // [8][64][64] bf16, row-swizzled
    short* wsh = dynsm + XLDSN;          // [8][NODESTR]
    __shared__ float bias_s[NT][C_OUT];

    const int tid   = threadIdx.x;
    const int wave  = tid >> 6;          // 0..15
    const int lane  = tid & 63;
    const int l16   = lane & 15;
    const int g     = lane >> 4;
    const int node  = wave & (NT - 1);
    const int thalf = wave >> 3;
    const int ts0   = thalf * 32;

    int bn0 = blockIdx.x * (NT * GRPS);  // advances by NT per group

    // ---- x prefetch registers: 8 float4 per lane, static indices only ----
    float4 xr[8];
    auto stage_load = [&](int bnb) {     // issue 8 independent global loads
        const float* xsrc = x + (size_t)(bnb + node) * (64 * C_IN);
        #pragma unroll
        for (int i = 0; i < 4; ++i) {
            const int gi = i * 64 + lane;          // 0..255 granules (32 t x 8)
            const int tl = ts0 + (gi >> 3);
            const int gr = gi & 7;
            xr[2 * i]     = *reinterpret_cast<const float4*>(xsrc + tl * 64 + gr * 8);
            xr[2 * i + 1] = *reinterpret_cast<const float4*>(xsrc + tl * 64 + gr * 8 + 4);
        }
    };
    auto stage_write = [&]() {           // cvt + swizzled ds_write (waits vmcnt)
        short* xdst = xsh + node * 4096;
        #pragma unroll
        for (int i = 0; i < 4; ++i) {
            const int gi = i * 64 + lane;
            const int tl = ts0 + (gi >> 3);
            const int gr = gi & 7;
            const int so = (gr * 8) ^ ((tl & 7) << 3);
            *reinterpret_cast<bf16x8*>(xdst + tl * 64 + so) = cvt8(xr[2 * i], xr[2 * i + 1]);
        }
    };

    auto calc_bias = [&](int bnb) {      // tid < 512: one (node,o) per thread
        if (tid < NT * C_OUT) {
            const int bnode = tid >> 6;
            const int o     = tid & 63;
            const float* mrow = meta + (size_t)(bnb + bnode) * M_DIM;
            const float* brow = blw + o * M_DIM;
            float s = blb[o];
            #pragma unroll
            for (int m = 0; m < M_DIM; ++m) s += mrow[m] * brow[m];
            bias_s[bnode][o] = s;
        }
    };
    auto load_metaF = [&](int bnb) -> bf16x8 {
        const float* mp = meta + (size_t)(bnb + (l16 & (NT - 1))) * M_DIM + g * 8;
        return cvt8(*reinterpret_cast<const float4*>(mp),
                    *reinterpret_cast<const float4*>(mp + 4));
    };

    bf16x8 metaF;

    // ---- prologue: group 0's x + bias + metaF ----
    stage_load(bn0);
    calc_bias(bn0);
    metaF = load_metaF(bn0);
    stage_write();
    barrier_lgkm();                      // xsh + bias ready

    const f32x4 ZV = {0.f, 0.f, 0.f, 0.f};

    #pragma unroll 1
    for (int grp = 0; grp < GRPS; ++grp) {
        f32x4 acc[2][4];                 // [t-tile local][o-tile] — static idx
        #pragma unroll
        for (int t = 0; t < 2; ++t)
            #pragma unroll
            for (int o = 0; o < 4; ++o) acc[t][o] = ZV;

        #pragma unroll 1
        for (int cchunk = 0; cchunk < 2; ++cchunk) {
            const int c0 = cchunk * 32;
            #pragma unroll
            for (int oh = 0; oh < 2; ++oh) {

                // ---- hyper: 12 tiles/wave = 2 groups of 6 (r6 form) ----
                #pragma unroll 1
                for (int ou = 0; ou < 2; ++ou) {
                    const int o_l = wave * 2 + ou;       // 0..31 within half
                    const int og  = oh * 32 + o_l;       // global o
                    #pragma unroll
                    for (int ch = 0; ch < 2; ++ch) {
                        #pragma unroll
                        for (int k = 0; k < 3; ++k) {
                            const int pr = og * 192 + (c0 + ch * 16 + l16) * 3 + k;
                            bf16x8 aF;
                            f32x4 Cf;
                            if constexpr (USE_WS) {
                                aF = *reinterpret_cast<const bf16x8*>(wlwbf + (size_t)pr * M_DIM + g * 8);
                                const float4 cf = *reinterpret_cast<const float4*>(
                                    wlbR + (og * 3 + k) * 64 + c0 + ch * 16 + g * 4);
                                Cf[0] = cf.x; Cf[1] = cf.y; Cf[2] = cf.z; Cf[3] = cf.w;
                            } else {
                                const float* wp = wlw + (size_t)pr * M_DIM + g * 8;
                                aF = cvt8(*reinterpret_cast<const float4*>(wp),
                                          *reinterpret_cast<const float4*>(wp + 4));
                                const int cb = c0 + ch * 16 + g * 4;
                                const int pb = og * 192 + k;
                                Cf[0] = wlb[pb + (cb + 0) * 3];
                                Cf[1] = wlb[pb + (cb + 1) * 3];
                                Cf[2] = wlb[pb + (cb + 2) * 3];
                                Cf[3] = wlb[pb + (cb + 3) * 3];
                            }
                            const f32x4 d = __builtin_amdgcn_mfma_f32_16x16x32_bf16(aF, metaF, Cf, 0, 0, 0);
                            if (l16 < NT) {
                                const int off = l16 * NODESTR + o_l * OSTR + k * 32 + ch * 16 + g * 4;
                                *reinterpret_cast<short4*>(&wsh[off]) =
                                    make_short4(f2bf(d[0]), f2bf(d[1]), f2bf(d[2]), f2bf(d[3]));
                            }
                        }
                    }
                }

                // T14: issue next group's x loads during the LAST phase; they
                // stay in flight across the lgkm-only barriers below.
                if (cchunk == 1 && oh == 1 && grp != GRPS - 1)
                    stage_load(bn0 + NT);

                barrier_lgkm();          // w ready for conv (LDS only)

                // ---- conv: B[2][3] + swizzled A, 12 MFMA (r6 form) ----
                const short* wn = wsh + node * NODESTR;
                const short* xn = xsh + node * 4096;
                bf16x8 B[2][3];
                #pragma unroll
                for (int ol = 0; ol < 2; ++ol)
                    #pragma unroll
                    for (int k = 0; k < 3; ++k)
                        B[ol][k] = *reinterpret_cast<const bf16x8*>(
                            wn + (ol * 16 + l16) * OSTR + k * 32 + g * 8);

                #pragma unroll
                for (int ttl = 0; ttl < 2; ++ttl) {
                    #pragma unroll
                    for (int k = 0; k < 3; ++k) {
                        int row = thalf * 32 + ttl * 16 + l16 + k;
                        row = row < 63 ? row : 63;     // rows t>=62 discarded
                        const int so = (c0 + g * 8) ^ ((row & 7) << 3);
                        const bf16x8 A = *reinterpret_cast<const bf16x8*>(
                            xn + row * 64 + so);
                        #pragma unroll
                        for (int ol = 0; ol < 2; ++ol)
                            acc[ttl][oh * 2 + ol] = __builtin_amdgcn_mfma_f32_16x16x32_bf16(
                                A, B[ol][k], acc[ttl][oh * 2 + ol], 0, 0, 0);
                    }
                }
                barrier_lgkm();          // conv reads done before next hyper
            }
        }

        // ---- epilogue: add bias, store f32 (overlaps next group's loads) ----
        float* ob = out + (size_t)(bn0 + node) * (S_OUT * C_OUT);
        #pragma unroll
        for (int ttl = 0; ttl < 2; ++ttl) {
            #pragma unroll
            for (int ot = 0; ot < 4; ++ot) {
                const int o  = ot * 16 + l16;
                const float bv = bias_s[node][o];
                #pragma unroll
                for (int r = 0; r < 4; ++r) {
                    const int t = thalf * 32 + ttl * 16 + g * 4 + r;
                    if (t < S_OUT) ob[t * C_OUT + o] = acc[ttl][ot][r] + bv;
                }
            }
        }

        // ---- inter-group: rotate to group g+1 ----
        if (grp != GRPS - 1) {
            barrier_lgkm();              // bias_s reads (epilogue) done
            bn0 += NT;
            calc_bias(bn0);
            metaF = load_metaF(bn0);
            stage_write();               // per-wave vmcnt wait on xr here
            barrier_lgkm();              // xsh + bias ready for next group
        }
    }
}

extern "C" void kernel_launch(void* const* d_in, const int* in_sizes, int n_in,
                              void* d_out, int out_size, void* d_ws, size_t ws_size,
                              hipStream_t stream) {
    const float* meta = (const float*)d_in[0];
    const float* x    = (const float*)d_in[1];
    const float* wlw  = (const float*)d_in[2];
    const float* wlb  = (const float*)d_in[3];
    const float* blw  = (const float*)d_in[4];
    const float* blb  = (const float*)d_in[5];
    float* out = (float*)d_out;
    (void)in_sizes; (void)n_in; (void)out_size;

    short* wlwbf = (short*)d_ws;
    float* wlbR  = (float*)((char*)d_ws + (size_t)WLW_ROWS * M_DIM * 2);

    const int grid = BN_TOT / (NT * GRPS);   // 256 persistent blocks

    if (ws_size >= (size_t)WS_NEED) {
        (void)hipFuncSetAttribute((const void*)&metaconv_fused<1>,
                                  hipFuncAttributeMaxDynamicSharedMemorySize, DYNB);
        wlw_to_bf16<<<dim3(WLW_ROWS * M_DIM / (256 * 8)), dim3(256), 0, stream>>>(wlw, wlwbf);
        wlb_rearr<<<dim3(WLW_ROWS / 256), dim3(256), 0, stream>>>(wlb, wlbR);
        metaconv_fused<1><<<dim3(grid), dim3(NTHREADS), DYNB, stream>>>(
            meta, x, wlw, wlwbf, wlb, wlbR, blw, blb, out);
    } else {
        (void)hipFuncSetAttribute((const void*)&metaconv_fused<0>,
                                  hipFuncAttributeMaxDynamicSharedMemorySize, DYNB);
        metaconv_fused<0><<<dim3(grid), dim3(NTHREADS), DYNB, stream>>>(
            meta, x, wlw, wlwbf, wlb, wlbR, blw, blb, out);
    }
}

// Round 17
// 142.777 us; speedup vs baseline: 1.3980x; 1.3980x over previous
//
#include <hip/hip_runtime.h>
#include <hip/hip_bf16.h>

// MetaConv2d fused hypernetwork + dynamic conv, bf16 MFMA. FINAL (round-6
// structure; session best, reproduced at 140.2 / 143.2 us wall).
// out[bn,t,o] = sum_{c,k} x[bn,t+k,c] * w[bn,o,c,k] + bias[bn,o]
//   w[bn,p]   = meta[bn,:]·w_lin_w[p,:] + w_lin_b[p],  p = o*192 + c*3 + k
//
// Block = 8 nodes, 1024 threads (16 waves = 8 nodes x 2 t-halves), grid 1024.
//  - x slab staged once into LDS as bf16 with a deep load queue (8 independent
//    float4 loads/lane) -> HBM latency covered at block start.
//  - xsh XOR-swizzled (idx ^= (row&7)<<3, write AND read) -> A-reads 2-way.
//  - all acc indices compile-time (runtime-indexed acc goes to scratch).
// Phases (4 = 2 c-chunks x 2 o-halves):
//   { hyper (12 tiles/wave, 2 groups of 6) -> w_lds; barrier;
//     conv (6 B + 6 A ds_reads, 12 MFMA into persistent acc); barrier; }
// LDS: dynamic 119 KB = x 64 KB + w 53.4 KB; static 2 KB bias.
//
// Session ledger (16 rounds): x-LDS staging+swizzle was the one real win
// (+12%); pipelining/occupancy/TLP/two-pass streaming/persistent-prefetch all
// neutral or regressed (spill gate: any extra >=24-reg state across the MFMA
// phases goes to scratch at this block shape). Conv consumption floors at
// ~130us in every structure tried -> fused form wins (hyper rides under it).

#define BN_TOT   8192
#define C_IN     64
#define C_OUT    64
#define M_DIM    32
#define S_OUT    62

#define NT       8            // nodes per block
#define NTHREADS 1024         // 16 waves
#define OSTR     104          // shorts per o-row in w_lds: 96 j + 8 pad (13 dwords: odd -> conflict-free)
#define NODESTR  3336         // 32*OSTR + 8
#define WLDSN    (NT * NODESTR)      // 26688 shorts
#define XLDSN    (NT * 64 * 64)      // 32768 shorts (x bf16, [node][t][c] swizzled)
#define DYNB     ((XLDSN + WLDSN) * 2)   // 118912 B
#define WLW_ROWS 12288
#define WS_NEED  (WLW_ROWS * M_DIM * 2 + WLW_ROWS * 4)

typedef __attribute__((ext_vector_type(8))) short bf16x8;
typedef __attribute__((ext_vector_type(4))) float f32x4;

static __device__ __forceinline__ short f2bf(float f) {
    return __bfloat16_as_short(__float2bfloat16(f));
}

static __device__ __forceinline__ bf16x8 cvt8(float4 a, float4 b) {
    bf16x8 r;
    r[0] = f2bf(a.x); r[1] = f2bf(a.y); r[2] = f2bf(a.z); r[3] = f2bf(a.w);
    r[4] = f2bf(b.x); r[5] = f2bf(b.y); r[6] = f2bf(b.z); r[7] = f2bf(b.w);
    return r;
}

// ---------------- pre-pass 1: w_lin_w f32 -> bf16 ----------------
extern "C" __global__ void wlw_to_bf16(const float* __restrict__ src,
                                       short* __restrict__ dst) {
    const int i = (blockIdx.x * 256 + threadIdx.x) * 8;
    const float4 a = *reinterpret_cast<const float4*>(src + i);
    const float4 b = *reinterpret_cast<const float4*>(src + i + 4);
    *reinterpret_cast<bf16x8*>(dst + i) = cvt8(a, b);
}

// ---------------- pre-pass 2: wlb -> wlbR[o][k][c] f32 ----------------
extern "C" __global__ void wlb_rearr(const float* __restrict__ wlb,
                                     float* __restrict__ wlbR) {
    const int i = blockIdx.x * 256 + threadIdx.x;
    const int o = i / 192;
    const int r = i - o * 192;
    const int k = r >> 6;
    const int c = r & 63;
    wlbR[i] = wlb[o * 192 + c * 3 + k];
}

// ---------------- fused kernel ----------------
template <int USE_WS>
__global__ void __launch_bounds__(NTHREADS, 4)
metaconv_fused(const float* __restrict__ meta,   // [8192][32]
               const float* __restrict__ x,      // [8192][64][64]
               const float* __restrict__ wlw,    // [12288][32] f32
               const short* __restrict__ wlwbf,  // [12288][32] bf16 (ws)
               const float* __restrict__ wlb,    // [12288]
               const float* __restrict__ wlbR,   // [64][3][64] (ws)
               const float* __restrict__ blw,    // [64][32]
               const float* __restrict__ blb,    // [64]
               float* __restrict__ out)          // [8192][62][64]
{
    extern __shared__ __align__(16) short dynsm[];
    short* xsh = dynsm;                  // [8][64][64] bf16, row-swizzled
    short* wsh = dynsm + XLDSN;          // [8][NODESTR]
    __shared__ float bias_s[NT][C_OUT];

    const int tid   = threadIdx.x;
    const int wave  = tid >> 6;          // 0..15
    const int lane  = tid & 63;
    const int l16   = lane & 15;
    const int g     = lane >> 4;
    const int node  = wave & (NT - 1);
    const int thalf = wave >> 3;
    const int bn0   = blockIdx.x * NT;

    // ---- stage x slab: 8 independent float4 loads/lane (deep HBM queue) ----
    // xsh layout: node*4096 + t*64 + (granule*8 ^ ((t&7)<<3))   [shorts]
    {
        const float* xsrc = x + (size_t)(bn0 + node) * (64 * C_IN);
        short* xdst = xsh + node * 4096;
        const int ts0 = thalf * 32;
        #pragma unroll
        for (int i = 0; i < 4; ++i) {
            const int gi = i * 64 + lane;          // 0..255 granules (32 t x 8)
            const int tl = ts0 + (gi >> 3);
            const int gr = gi & 7;
            const float4 a = *reinterpret_cast<const float4*>(xsrc + tl * 64 + gr * 8);
            const float4 b = *reinterpret_cast<const float4*>(xsrc + tl * 64 + gr * 8 + 4);
            const int so = (gr * 8) ^ ((tl & 7) << 3);
            *reinterpret_cast<bf16x8*>(xdst + tl * 64 + so) = cvt8(a, b);
        }
    }

    // per-block bias table (tid < 512)
    if (tid < NT * C_OUT) {
        const int bnode = tid >> 6;
        const int o     = tid & 63;
        const float* mrow = meta + (size_t)(bn0 + bnode) * M_DIM;
        const float* brow = blw + o * M_DIM;
        float s = blb[o];
        #pragma unroll
        for (int m = 0; m < M_DIM; ++m) s += mrow[m] * brow[m];
        bias_s[bnode][o] = s;
    }

    // meta B-fragment (cols = nodes; cols 8..15 duplicate, discarded on write)
    bf16x8 metaF;
    {
        const float* mp = meta + (size_t)(bn0 + (l16 & (NT - 1))) * M_DIM + g * 8;
        metaF = cvt8(*reinterpret_cast<const float4*>(mp),
                     *reinterpret_cast<const float4*>(mp + 4));
    }

    const f32x4 ZV = {0.f, 0.f, 0.f, 0.f};
    f32x4 acc[2][4];                     // [t-tile local][o-tile 0..3] — static idx only
    #pragma unroll
    for (int t = 0; t < 2; ++t)
        #pragma unroll
        for (int o = 0; o < 4; ++o) acc[t][o] = ZV;

    __syncthreads();                     // x staged, bias ready

    #pragma unroll 1
    for (int cchunk = 0; cchunk < 2; ++cchunk) {
        const int c0 = cchunk * 32;
        #pragma unroll
        for (int oh = 0; oh < 2; ++oh) {   // compile-time: acc index static

            // ---- hyper: 12 tiles/wave = 2 groups of 6 ----
            #pragma unroll 1
            for (int ou = 0; ou < 2; ++ou) {
                const int o_l = wave * 2 + ou;       // 0..31 within half
                const int og  = oh * 32 + o_l;       // global o
                #pragma unroll
                for (int ch = 0; ch < 2; ++ch) {
                    #pragma unroll
                    for (int k = 0; k < 3; ++k) {
                        const int pr = og * 192 + (c0 + ch * 16 + l16) * 3 + k;
                        bf16x8 aF;
                        f32x4 Cf;
                        if constexpr (USE_WS) {
                            aF = *reinterpret_cast<const bf16x8*>(wlwbf + (size_t)pr * M_DIM + g * 8);
                            const float4 cf = *reinterpret_cast<const float4*>(
                                wlbR + (og * 3 + k) * 64 + c0 + ch * 16 + g * 4);
                            Cf[0] = cf.x; Cf[1] = cf.y; Cf[2] = cf.z; Cf[3] = cf.w;
                        } else {
                            const float* wp = wlw + (size_t)pr * M_DIM + g * 8;
                            aF = cvt8(*reinterpret_cast<const float4*>(wp),
                                      *reinterpret_cast<const float4*>(wp + 4));
                            const int cb = c0 + ch * 16 + g * 4;
                            const int pb = og * 192 + k;
                            Cf[0] = wlb[pb + (cb + 0) * 3];
                            Cf[1] = wlb[pb + (cb + 1) * 3];
                            Cf[2] = wlb[pb + (cb + 2) * 3];
                            Cf[3] = wlb[pb + (cb + 3) * 3];
                        }
                        const f32x4 d = __builtin_amdgcn_mfma_f32_16x16x32_bf16(aF, metaF, Cf, 0, 0, 0);
                        if (l16 < NT) {
                            const int off = l16 * NODESTR + o_l * OSTR + k * 32 + ch * 16 + g * 4;
                            *reinterpret_cast<short4*>(&wsh[off]) =
                                make_short4(f2bf(d[0]), f2bf(d[1]), f2bf(d[2]), f2bf(d[3]));
                        }
                    }
                }
            }
            __syncthreads();             // w ready for conv

            // ---- conv: B-frags (LDS), A-frags (swizzled LDS), 12 MFMA ----
            const short* wn = wsh + node * NODESTR;
            const short* xn = xsh + node * 4096;
            bf16x8 B[2][3];
            #pragma unroll
            for (int ol = 0; ol < 2; ++ol)
                #pragma unroll
                for (int k = 0; k < 3; ++k)
                    B[ol][k] = *reinterpret_cast<const bf16x8*>(
                        wn + (ol * 16 + l16) * OSTR + k * 32 + g * 8);

            #pragma unroll
            for (int ttl = 0; ttl < 2; ++ttl) {
                #pragma unroll
                for (int k = 0; k < 3; ++k) {
                    int row = thalf * 32 + ttl * 16 + l16 + k;
                    row = row < 63 ? row : 63;         // rows t>=62 discarded
                    const int so = (c0 + g * 8) ^ ((row & 7) << 3);
                    const bf16x8 A = *reinterpret_cast<const bf16x8*>(
                        xn + row * 64 + so);
                    #pragma unroll
                    for (int ol = 0; ol < 2; ++ol)
                        acc[ttl][oh * 2 + ol] = __builtin_amdgcn_mfma_f32_16x16x32_bf16(
                            A, B[ol][k], acc[ttl][oh * 2 + ol], 0, 0, 0);
                }
            }
            __syncthreads();             // conv done before next hyper overwrite
        }
    }

    // ---------------- epilogue: add bias, store f32 ----------------
    float* ob = out + (size_t)(bn0 + node) * (S_OUT * C_OUT);
    #pragma unroll
    for (int ttl = 0; ttl < 2; ++ttl) {
        #pragma unroll
        for (int ot = 0; ot < 4; ++ot) {
            const int o  = ot * 16 + l16;
            const float bv = bias_s[node][o];
            #pragma unroll
            for (int r = 0; r < 4; ++r) {
                const int t = thalf * 32 + ttl * 16 + g * 4 + r;
                if (t < S_OUT) ob[t * C_OUT + o] = acc[ttl][ot][r] + bv;
            }
        }
    }
}

extern "C" void kernel_launch(void* const* d_in, const int* in_sizes, int n_in,
                              void* d_out, int out_size, void* d_ws, size_t ws_size,
                              hipStream_t stream) {
    const float* meta = (const float*)d_in[0];
    const float* x    = (const float*)d_in[1];
    const float* wlw  = (const float*)d_in[2];
    const float* wlb  = (const float*)d_in[3];
    const float* blw  = (const float*)d_in[4];
    const float* blb  = (const float*)d_in[5];
    float* out = (float*)d_out;
    (void)in_sizes; (void)n_in; (void)out_size;

    short* wlwbf = (short*)d_ws;
    float* wlbR  = (float*)((char*)d_ws + (size_t)WLW_ROWS * M_DIM * 2);

    if (ws_size >= (size_t)WS_NEED) {
        (void)hipFuncSetAttribute((const void*)&metaconv_fused<1>,
                                  hipFuncAttributeMaxDynamicSharedMemorySize, DYNB);
        wlw_to_bf16<<<dim3(WLW_ROWS * M_DIM / (256 * 8)), dim3(256), 0, stream>>>(wlw, wlwbf);
        wlb_rearr<<<dim3(WLW_ROWS / 256), dim3(256), 0, stream>>>(wlb, wlbR);
        metaconv_fused<1><<<dim3(BN_TOT / NT), dim3(NTHREADS), DYNB, stream>>>(
            meta, x, wlw, wlwbf, wlb, wlbR, blw, blb, out);
    } else {
        (void)hipFuncSetAttribute((const void*)&metaconv_fused<0>,
                                  hipFuncAttributeMaxDynamicSharedMemorySize, DYNB);
        metaconv_fused<0><<<dim3(BN_TOT / NT), dim3(NTHREADS), DYNB, stream>>>(
            meta, x, wlw, wlwbf, wlb, wlbR, blw, blb, out);
    }
}

// Round 18
// 139.509 us; speedup vs baseline: 1.4307x; 1.0234x over previous
//
#include <hip/hip_runtime.h>
#include <hip/hip_bf16.h>

// MetaConv2d fused hypernetwork + dynamic conv, bf16 MFMA. Round 18.
// = round-6 (session best, 140-143us) with ONE reorder: the x-stage is split
// into load (block's FIRST instructions, 8 independent float4 -> 32 regs) and
// write (after hyper phase 0), and hyper(0) is hoisted into the prologue.
// hyper needs only wlwbf+metaF, not xsh -> the ~13k-cyc serial x-stage head
// (nothing overlaps it at 1 block/CU) hides under hyper(0)+bias.
// xr live range is ONLY bias+metaF+hyper(0) (acc not yet initialized), peak
// ~80 regs -- unlike r16's cross-group version which spilled.
// Main loop: conv(p); sync; hyper(p+1); sync  -- same barriers, same bodies.
//
// Everything else identical to r6: 8 nodes/block, 1024 thr (16 waves =
// node x t-half), 4 phases (2 c-chunks x 2 o-halves), hyper 12 tiles/wave
// (2 groups of 6), conv B[2][3] + XOR-swizzled A, static acc[2][4],
// LDS dynamic 119 KB (x 64 KB swizzled + w 53.4 KB) + 2 KB bias.

#define BN_TOT   8192
#define C_IN     64
#define C_OUT    64
#define M_DIM    32
#define S_OUT    62

#define NT       8            // nodes per block
#define NTHREADS 1024         // 16 waves
#define OSTR     104          // shorts per o-row in w_lds (96 j + 8 pad, odd dwords)
#define NODESTR  3336         // 32*OSTR + 8
#define WLDSN    (NT * NODESTR)      // 26688 shorts
#define XLDSN    (NT * 64 * 64)      // 32768 shorts (x bf16, swizzled)
#define DYNB     ((XLDSN + WLDSN) * 2)   // 118912 B
#define WLW_ROWS 12288
#define WS_NEED  (WLW_ROWS * M_DIM * 2 + WLW_ROWS * 4)

typedef __attribute__((ext_vector_type(8))) short bf16x8;
typedef __attribute__((ext_vector_type(4))) float f32x4;

static __device__ __forceinline__ short f2bf(float f) {
    return __bfloat16_as_short(__float2bfloat16(f));
}

static __device__ __forceinline__ bf16x8 cvt8(float4 a, float4 b) {
    bf16x8 r;
    r[0] = f2bf(a.x); r[1] = f2bf(a.y); r[2] = f2bf(a.z); r[3] = f2bf(a.w);
    r[4] = f2bf(b.x); r[5] = f2bf(b.y); r[6] = f2bf(b.z); r[7] = f2bf(b.w);
    return r;
}

// ---------------- pre-pass 1: w_lin_w f32 -> bf16 ----------------
extern "C" __global__ void wlw_to_bf16(const float* __restrict__ src,
                                       short* __restrict__ dst) {
    const int i = (blockIdx.x * 256 + threadIdx.x) * 8;
    const float4 a = *reinterpret_cast<const float4*>(src + i);
    const float4 b = *reinterpret_cast<const float4*>(src + i + 4);
    *reinterpret_cast<bf16x8*>(dst + i) = cvt8(a, b);
}

// ---------------- pre-pass 2: wlb -> wlbR[o][k][c] f32 ----------------
extern "C" __global__ void wlb_rearr(const float* __restrict__ wlb,
                                     float* __restrict__ wlbR) {
    const int i = blockIdx.x * 256 + threadIdx.x;
    const int o = i / 192;
    const int r = i - o * 192;
    const int k = r >> 6;
    const int c = r & 63;
    wlbR[i] = wlb[o * 192 + c * 3 + k];
}

// ---------------- fused kernel ----------------
template <int USE_WS>
__global__ void __launch_bounds__(NTHREADS, 4)
metaconv_fused(const float* __restrict__ meta,   // [8192][32]
               const float* __restrict__ x,      // [8192][64][64]
               const float* __restrict__ wlw,    // [12288][32] f32
               const short* __restrict__ wlwbf,  // [12288][32] bf16 (ws)
               const float* __restrict__ wlb,    // [12288]
               const float* __restrict__ wlbR,   // [64][3][64] (ws)
               const float* __restrict__ blw,    // [64][32]
               const float* __restrict__ blb,    // [64]
               float* __restrict__ out)          // [8192][62][64]
{
    extern __shared__ __align__(16) short dynsm[];
    short* xsh = dynsm;                  // [8][64][64] bf16, row-swizzled
    short* wsh = dynsm + XLDSN;          // [8][NODESTR]
    __shared__ float bias_s[NT][C_OUT];

    const int tid   = threadIdx.x;
    const int wave  = tid >> 6;          // 0..15
    const int lane  = tid & 63;
    const int l16   = lane & 15;
    const int g     = lane >> 4;
    const int node  = wave & (NT - 1);
    const int thalf = wave >> 3;
    const int ts0   = thalf * 32;
    const int bn0   = blockIdx.x * NT;

    // ---- FIRST instructions: issue the 8 x loads (deep HBM queue).
    // Consumed only after hyper(0): HBM latency hides under bias+metaF+hyper.
    float4 xr[8];                        // static indices only (rule #20)
    {
        const float* xsrc = x + (size_t)(bn0 + node) * (64 * C_IN);
        #pragma unroll
        for (int i = 0; i < 4; ++i) {
            const int gi = i * 64 + lane;          // 0..255 granules (32 t x 8)
            const int tl = ts0 + (gi >> 3);
            const int gr = gi & 7;
            xr[2 * i]     = *reinterpret_cast<const float4*>(xsrc + tl * 64 + gr * 8);
            xr[2 * i + 1] = *reinterpret_cast<const float4*>(xsrc + tl * 64 + gr * 8 + 4);
        }
    }

    // per-block bias table (tid < 512) — independent of x loads
    if (tid < NT * C_OUT) {
        const int bnode = tid >> 6;
        const int o     = tid & 63;
        const float* mrow = meta + (size_t)(bn0 + bnode) * M_DIM;
        const float* brow = blw + o * M_DIM;
        float s = blb[o];
        #pragma unroll
        for (int m = 0; m < M_DIM; ++m) s += mrow[m] * brow[m];
        bias_s[bnode][o] = s;
    }

    // meta B-fragment (cols = nodes; cols 8..15 duplicate, discarded on write)
    bf16x8 metaF;
    {
        const float* mp = meta + (size_t)(bn0 + (l16 & (NT - 1))) * M_DIM + g * 8;
        metaF = cvt8(*reinterpret_cast<const float4*>(mp),
                     *reinterpret_cast<const float4*>(mp + 4));
    }

    // hyper for one phase (c0, oh): 12 tiles/wave = 2 groups of 6 (r6 form).
    // D lane(l16,g): col=node=l16 (valid l16<NT), rows cc_local = ch*16+g*4+r.
    auto hyper = [&](int c0, int oh) {
        #pragma unroll 1
        for (int ou = 0; ou < 2; ++ou) {
            const int o_l = wave * 2 + ou;       // 0..31 within half
            const int og  = oh * 32 + o_l;       // global o
            #pragma unroll
            for (int ch = 0; ch < 2; ++ch) {
                #pragma unroll
                for (int k = 0; k < 3; ++k) {
                    const int pr = og * 192 + (c0 + ch * 16 + l16) * 3 + k;
                    bf16x8 aF;
                    f32x4 Cf;
                    if constexpr (USE_WS) {
                        aF = *reinterpret_cast<const bf16x8*>(wlwbf + (size_t)pr * M_DIM + g * 8);
                        const float4 cf = *reinterpret_cast<const float4*>(
                            wlbR + (og * 3 + k) * 64 + c0 + ch * 16 + g * 4);
                        Cf[0] = cf.x; Cf[1] = cf.y; Cf[2] = cf.z; Cf[3] = cf.w;
                    } else {
                        const float* wp = wlw + (size_t)pr * M_DIM + g * 8;
                        aF = cvt8(*reinterpret_cast<const float4*>(wp),
                                  *reinterpret_cast<const float4*>(wp + 4));
                        const int cb = c0 + ch * 16 + g * 4;
                        const int pb = og * 192 + k;
                        Cf[0] = wlb[pb + (cb + 0) * 3];
                        Cf[1] = wlb[pb + (cb + 1) * 3];
                        Cf[2] = wlb[pb + (cb + 2) * 3];
                        Cf[3] = wlb[pb + (cb + 3) * 3];
                    }
                    const f32x4 d = __builtin_amdgcn_mfma_f32_16x16x32_bf16(aF, metaF, Cf, 0, 0, 0);
                    if (l16 < NT) {
                        const int off = l16 * NODESTR + o_l * OSTR + k * 32 + ch * 16 + g * 4;
                        *reinterpret_cast<short4*>(&wsh[off]) =
                            make_short4(f2bf(d[0]), f2bf(d[1]), f2bf(d[2]), f2bf(d[3]));
                    }
                }
            }
        }
    };

    // ---- prologue: hyper(0,0) runs while x loads are in flight ----
    hyper(0, 0);

    // drain x loads: cvt + swizzled ds_write (xr dies here)
    {
        short* xdst = xsh + node * 4096;
        #pragma unroll
        for (int i = 0; i < 4; ++i) {
            const int gi = i * 64 + lane;
            const int tl = ts0 + (gi >> 3);
            const int gr = gi & 7;
            const int so = (gr * 8) ^ ((tl & 7) << 3);
            *reinterpret_cast<bf16x8*>(xdst + tl * 64 + so) = cvt8(xr[2 * i], xr[2 * i + 1]);
        }
    }

    const f32x4 ZV = {0.f, 0.f, 0.f, 0.f};
    f32x4 acc[2][4];                     // [t-tile local][o-tile] — static idx only
    #pragma unroll
    for (int t = 0; t < 2; ++t)
        #pragma unroll
        for (int o = 0; o < 4; ++o) acc[t][o] = ZV;

    __syncthreads();                     // xsh + wsh(phase0) + bias ready

    #pragma unroll 1
    for (int cchunk = 0; cchunk < 2; ++cchunk) {
        const int c0 = cchunk * 32;
        #pragma unroll
        for (int oh = 0; oh < 2; ++oh) {   // compile-time: acc index static

            // ---- conv: B-frags (LDS), A-frags (swizzled LDS), 12 MFMA ----
            const short* wn = wsh + node * NODESTR;
            const short* xn = xsh + node * 4096;
            bf16x8 B[2][3];
            #pragma unroll
            for (int ol = 0; ol < 2; ++ol)
                #pragma unroll
                for (int k = 0; k < 3; ++k)
                    B[ol][k] = *reinterpret_cast<const bf16x8*>(
                        wn + (ol * 16 + l16) * OSTR + k * 32 + g * 8);

            #pragma unroll
            for (int ttl = 0; ttl < 2; ++ttl) {
                #pragma unroll
                for (int k = 0; k < 3; ++k) {
                    int row = ts0 + ttl * 16 + l16 + k;
                    row = row < 63 ? row : 63;         // rows t>=62 discarded
                    const int so = (c0 + g * 8) ^ ((row & 7) << 3);
                    const bf16x8 A = *reinterpret_cast<const bf16x8*>(
                        xn + row * 64 + so);
                    #pragma unroll
                    for (int ol = 0; ol < 2; ++ol)
                        acc[ttl][oh * 2 + ol] = __builtin_amdgcn_mfma_f32_16x16x32_bf16(
                            A, B[ol][k], acc[ttl][oh * 2 + ol], 0, 0, 0);
                }
            }
            __syncthreads();             // conv reads done before next hyper

            // ---- hyper for the NEXT phase (skip after last) ----
            const bool last = (cchunk == 1) && (oh == 1);
            if (!last) {
                const int c0n = (oh == 1) ? c0 + 32 : c0;
                hyper(c0n, oh ^ 1);
                __syncthreads();         // w ready for next conv
            }
        }
    }

    // ---------------- epilogue: add bias, store f32 ----------------
    float* ob = out + (size_t)(bn0 + node) * (S_OUT * C_OUT);
    #pragma unroll
    for (int ttl = 0; ttl < 2; ++ttl) {
        #pragma unroll
        for (int ot = 0; ot < 4; ++ot) {
            const int o  = ot * 16 + l16;
            const float bv = bias_s[node][o];
            #pragma unroll
            for (int r = 0; r < 4; ++r) {
                const int t = ts0 + ttl * 16 + g * 4 + r;
                if (t < S_OUT) ob[t * C_OUT + o] = acc[ttl][ot][r] + bv;
            }
        }
    }
}

extern "C" void kernel_launch(void* const* d_in, const int* in_sizes, int n_in,
                              void* d_out, int out_size, void* d_ws, size_t ws_size,
                              hipStream_t stream) {
    const float* meta = (const float*)d_in[0];
    const float* x    = (const float*)d_in[1];
    const float* wlw  = (const float*)d_in[2];
    const float* wlb  = (const float*)d_in[3];
    const float* blw  = (const float*)d_in[4];
    const float* blb  = (const float*)d_in[5];
    float* out = (float*)d_out;
    (void)in_sizes; (void)n_in; (void)out_size;

    short* wlwbf = (short*)d_ws;
    float* wlbR  = (float*)((char*)d_ws + (size_t)WLW_ROWS * M_DIM * 2);

    if (ws_size >= (size_t)WS_NEED) {
        (void)hipFuncSetAttribute((const void*)&metaconv_fused<1>,
                                  hipFuncAttributeMaxDynamicSharedMemorySize, DYNB);
        wlw_to_bf16<<<dim3(WLW_ROWS * M_DIM / (256 * 8)), dim3(256), 0, stream>>>(wlw, wlwbf);
        wlb_rearr<<<dim3(WLW_ROWS / 256), dim3(256), 0, stream>>>(wlb, wlbR);
        metaconv_fused<1><<<dim3(BN_TOT / NT), dim3(NTHREADS), DYNB, stream>>>(
            meta, x, wlw, wlwbf, wlb, wlbR, blw, blb, out);
    } else {
        (void)hipFuncSetAttribute((const void*)&metaconv_fused<0>,
                                  hipFuncAttributeMaxDynamicSharedMemorySize, DYNB);
        metaconv_fused<0><<<dim3(BN_TOT / NT), dim3(NTHREADS), DYNB, stream>>>(
            meta, x, wlw, wlwbf, wlb, wlbR, blw, blb, out);
    }
}